// Round 8
// baseline (561.277 us; speedup 1.0000x reference)
//
#include <hip/hip_runtime.h>

typedef short s16x8 __attribute__((ext_vector_type(8)));
typedef unsigned short u16x8 __attribute__((ext_vector_type(8)));
typedef float f32x4 __attribute__((ext_vector_type(4)));
typedef unsigned short ushort;

// ---------------- problem constants ----------------
#define NTOK 1024
#define DHID 512

#define VH   20003
#define KH   512
#define VH_PAD 20480

#define V1   20000
#define K1   128
#define V1_PAD 20480

#define V2   160000
#define K2   32
#define V2_PAD 163840

#define V3   67735
#define K3   32
#define V3_PAD 68608

// partial-sum chunk counts (see gemm_lse_* epilogues)
#define NCHK_H 320     // 160 n-blocks x 2 col-halves
#define NCHK_1 320
#define NCHK_2 320     // 160 n-groups x 2
#define NCHK_3 134     // 67 n-groups x 2

#define PAD_BIAS (-1e30f)
#define LOG2E 1.4426950408889634f
#define LN2F  0.6931471805599453f

// Pipeline barrier that is ALSO a compiler fence (r6 inf bug: raw
// __builtin_amdgcn_s_barrier is not an LLVM memory fence; ds_reads were
// hoisted above it and raced other waves' in-flight global_load_lds).
#define PIPE_BARRIER() do {                                   \
        asm volatile("s_barrier" ::: "memory");               \
        __builtin_amdgcn_sched_barrier(0);                    \
    } while (0)

// ---------------- ws layout (bytes) ----------------
#define OFF_HW   0UL
#define OFF_W1   (OFF_HW  + (unsigned long)VH_PAD*KH*2)
#define OFF_W2   (OFF_W1  + (unsigned long)V1_PAD*K1*2)
#define OFF_W3   (OFF_W2  + (unsigned long)V2_PAD*K2*2)
#define OFF_HID  (OFF_W3  + (unsigned long)V3_PAD*K3*2)
#define OFF_PT0  (OFF_HID + (unsigned long)NTOK*DHID*2)
#define OFF_PT1  (OFF_PT0 + (unsigned long)512*DHID*2)
#define OFF_PT2  (OFF_PT1 + (unsigned long)128*DHID*2)
#define OFF_PT3  (OFF_PT2 + (unsigned long)32*DHID*2)
#define OFF_H0   (OFF_PT3 + (unsigned long)32*DHID*2)
#define OFF_H1   (OFF_H0  + (unsigned long)NTOK*512*2)
#define OFF_H2   (OFF_H1  + (unsigned long)NTOK*128*2)
#define OFF_H3   (OFF_H2  + (unsigned long)NTOK*32*2)
#define OFF_HB   (OFF_H3  + (unsigned long)NTOK*32*2)
#define OFF_B1   (OFF_HB  + (unsigned long)VH_PAD*4)
#define OFF_B2   (OFF_B1  + (unsigned long)V1_PAD*4)
#define OFF_B3   (OFF_B2  + (unsigned long)V2_PAD*4)
#define OFF_SH   (OFF_B3  + (unsigned long)V3_PAD*4)
#define OFF_S1   (OFF_SH  + (unsigned long)NTOK*NCHK_H*4)
#define OFF_S2   (OFF_S1  + (unsigned long)NTOK*NCHK_1*4)
#define OFF_S3   (OFF_S2  + (unsigned long)NTOK*NCHK_2*4)

// ---------------- helpers ----------------
__device__ __forceinline__ ushort f2bf(float f) {
    union { float f; unsigned u; } x; x.f = f;
    unsigned r = x.u + 0x7fffu + ((x.u >> 16) & 1u);
    return (ushort)(r >> 16);
}
__device__ __forceinline__ float bf2f(ushort h) {
    union { unsigned u; float f; } x; x.u = ((unsigned)h) << 16;
    return x.f;
}
__device__ __forceinline__ f32x4 mfma_bf16(s16x8 a, s16x8 b, f32x4 c) {
    return __builtin_amdgcn_mfma_f32_16x16x32_bf16(a, b, c, 0, 0, 0);
}
__device__ __forceinline__ void ld8(const float* p, float* v) {
    float4 a = *(const float4*)p, b = *(const float4*)(p + 4);
    v[0]=a.x; v[1]=a.y; v[2]=a.z; v[3]=a.w; v[4]=b.x; v[5]=b.y; v[6]=b.z; v[7]=b.w;
}
__device__ __forceinline__ void gld_lds16(const ushort* g, ushort* l) {
    __builtin_amdgcn_global_load_lds(
        (const __attribute__((address_space(1))) unsigned int*)g,
        (__attribute__((address_space(3))) unsigned int*)l, 16, 0, 0);
}

// ---------------- prep: wave-per-512-element-block swizzle ----------------
// W arrays pre-scaled by LOG2E so fused kernels use exp2; finalize scales by LN2.
#define WB_HW  20480L
#define WB_W1  5120L
#define WB_W2  10240L
#define WB_W3  4288L
#define WB_HID 1024L
#define WB_PT0 512L
#define WB_PT1 128L
#define WB_PT2 32L
#define WB_PT3 32L
#define WB_TOTAL (WB_HW+WB_W1+WB_W2+WB_W3+WB_HID+WB_PT0+WB_PT1+WB_PT2+WB_PT3)

__global__ __launch_bounds__(256) void prep_wswz(
    const float* __restrict__ hidden,
    const float* __restrict__ W0, const float* __restrict__ cw,
    const float* __restrict__ W1, const float* __restrict__ W2, const float* __restrict__ W3,
    const float* __restrict__ p0, const float* __restrict__ p1,
    const float* __restrict__ p2, const float* __restrict__ p3,
    ushort* __restrict__ hw, ushort* __restrict__ ow1,
    ushort* __restrict__ ow2, ushort* __restrict__ ow3,
    ushort* __restrict__ hid,
    ushort* __restrict__ pT0, ushort* __restrict__ pT1,
    ushort* __restrict__ pT2, ushort* __restrict__ pT3)
{
    int lane = threadIdx.x & 63;
    int r = lane & 15, quad = lane >> 4;
    long wb0 = (long)blockIdx.x * 4 + (threadIdx.x >> 6);
    long nw = (long)gridDim.x * 4;
    for (long wb = wb0; wb < WB_TOTAL; wb += nw) {
        long b = wb;
        float vals[8];
        #pragma unroll
        for (int j = 0; j < 8; ++j) vals[j] = 0.f;
        float scale = LOG2E;
        ushort* dst;
        if (b < WB_HW) {
            long tile = b >> 4, ks = b & 15;
            long v = tile * 16 + r, k = ks * 32 + quad * 8;
            if (v < 20000)      ld8(W0 + v * 512 + k, vals);
            else if (v < VH)    ld8(cw + (v - 20000) * 512 + k, vals);
            dst = hw + b * 512 + (long)lane * 8;
        } else if ((b -= WB_HW) < WB_W1) {
            long tile = b >> 2, ks = b & 3;
            long v = tile * 16 + r, k = ks * 32 + quad * 8;
            if (v < V1) ld8(W1 + v * 128 + k, vals);
            dst = ow1 + b * 512 + (long)lane * 8;
        } else if ((b -= WB_W1) < WB_W2) {
            long v = b * 16 + r;
            if (v < V2) ld8(W2 + v * 32 + quad * 8, vals);
            dst = ow2 + b * 512 + (long)lane * 8;
        } else if ((b -= WB_W2) < WB_W3) {
            long v = b * 16 + r;
            if (v < V3 && quad == 0) ld8(W3 + v * 8, vals);
            dst = ow3 + b * 512 + (long)lane * 8;
        } else if ((b -= WB_W3) < WB_HID) {
            scale = 1.f;
            long tile = b >> 4, ks = b & 15;
            long v = tile * 16 + r, k = ks * 32 + quad * 8;
            ld8(hidden + v * 512 + k, vals);
            dst = hid + b * 512 + (long)lane * 8;
        } else if ((b -= WB_HID) < WB_PT0) {
            scale = 1.f;
            long tile = b >> 4, ks = b & 15;
            long c = tile * 16 + r, k = ks * 32 + quad * 8;
            #pragma unroll
            for (int j = 0; j < 8; ++j) vals[j] = p0[(k + j) * 512 + c];
            dst = pT0 + b * 512 + (long)lane * 8;
        } else if ((b -= WB_PT0) < WB_PT1) {
            scale = 1.f;
            long tile = b >> 4, ks = b & 15;
            long c = tile * 16 + r, k = ks * 32 + quad * 8;
            #pragma unroll
            for (int j = 0; j < 8; ++j) vals[j] = p1[(k + j) * 128 + c];
            dst = pT1 + b * 512 + (long)lane * 8;
        } else if ((b -= WB_PT1) < WB_PT2) {
            scale = 1.f;
            long tile = b >> 4, ks = b & 15;
            long c = tile * 16 + r, k = ks * 32 + quad * 8;
            #pragma unroll
            for (int j = 0; j < 8; ++j) vals[j] = p2[(k + j) * 32 + c];
            dst = pT2 + b * 512 + (long)lane * 8;
        } else {
            scale = 1.f;
            b -= WB_PT2;
            long tile = b >> 4, ks = b & 15;
            long c = tile * 16 + r, k = ks * 32 + quad * 8;
            if (c < 8) {
                #pragma unroll
                for (int j = 0; j < 8; ++j) vals[j] = p3[(k + j) * 8 + c];
            }
            dst = pT3 + b * 512 + (long)lane * 8;
        }
        u16x8 o;
        #pragma unroll
        for (int j = 0; j < 8; ++j) o[j] = f2bf(vals[j] * scale);
        *(u16x8*)dst = o;
    }
}

// ---------------- prep: padded biases (pre-scaled by LOG2E) ----------------
#define E_HB  ((long)VH_PAD)
#define E_B1  ((long)V1_PAD)
#define E_B2  ((long)V2_PAD)
#define E_B3  ((long)V3_PAD)
#define E_BIAS (E_HB+E_B1+E_B2+E_B3)

__global__ __launch_bounds__(256) void prep_bias(
    const float* __restrict__ b0, const float* __restrict__ b1,
    const float* __restrict__ b2, const float* __restrict__ b3,
    const float* __restrict__ cb,
    float* __restrict__ hbp, float* __restrict__ ob1,
    float* __restrict__ ob2, float* __restrict__ ob3)
{
    long stride = (long)gridDim.x * blockDim.x;
    for (long i = (long)blockIdx.x * blockDim.x + threadIdx.x; i < E_BIAS; i += stride) {
        long j = i;
        if (j < E_HB) {
            hbp[j] = ((j < 20000) ? b0[j] : (j < VH) ? cb[j - 20000] : PAD_BIAS) * LOG2E;
        } else if ((j -= E_HB) < E_B1) {
            ob1[j] = ((j < V1) ? b1[j] : PAD_BIAS) * LOG2E;
        } else if ((j -= E_B1) < E_B2) {
            ob2[j] = ((j < V2) ? b2[j] : PAD_BIAS) * LOG2E;
        } else { j -= E_B2;
            ob3[j] = ((j < V3) ? b3[j] : PAD_BIAS) * LOG2E;
        }
    }
}

// ---------------- gemm_h body + merged launch ----------------
__device__ __forceinline__ void gemm_body(
    const ushort* __restrict__ A, const ushort* __restrict__ Bt,
    ushort* __restrict__ Hout, int dpad, int c_tile)
{
    int wave = threadIdx.x >> 6, lane = threadIdx.x & 63;
    int quad = lane >> 4, colid = lane & 15;
    int m_tile = blockIdx.x * 4 + wave;
    const ushort* Ab = A + ((long)m_tile * 16) * 512 + lane * 8;
    const ushort* Bb = Bt + ((long)c_tile * 16) * 512 + lane * 8;
    f32x4 acc = {0.f, 0.f, 0.f, 0.f};
    #pragma unroll
    for (int ks = 0; ks < 16; ++ks) {
        s16x8 a = *(const s16x8*)(Ab + ks * 512);
        s16x8 b = *(const s16x8*)(Bb + ks * 512);
        acc = mfma_bf16(a, b, acc);
    }
    int KBo = dpad >> 5;
    int col = c_tile * 16 + colid;
    int ks_o = col >> 5, q_o = (col >> 3) & 3, j_o = col & 7;
    #pragma unroll
    for (int r = 0; r < 4; ++r) {
        int rm = quad * 4 + r;
        Hout[((long)m_tile * KBo + ks_o) * 512 + (q_o * 16 + rm) * 8 + j_o] = f2bf(acc[r]);
    }
}

__global__ __launch_bounds__(256) void gemm_all(
    const ushort* __restrict__ hid,
    const ushort* __restrict__ pT0, const ushort* __restrict__ pT1,
    const ushort* __restrict__ pT2, const ushort* __restrict__ pT3,
    ushort* __restrict__ H0, ushort* __restrict__ H1,
    ushort* __restrict__ H2, ushort* __restrict__ H3)
{
    int y = blockIdx.y;
    if (y < 32)      gemm_body(hid, pT0, H0, 512, y);
    else if (y < 40) gemm_body(hid, pT1, H1, 128, y - 32);
    else if (y < 42) gemm_body(hid, pT2, H2, 32,  y - 40);
    else             gemm_body(hid, pT3, H3, 32,  y - 42);
}

// ============ gemm_lse_k: 128x128 tile, K-pipelined (head KB=16, tail1 KB=4) =========
// (256,2) + fenced barriers — PASSED r7 and fell out of the top-5; unchanged.
template<int KB>
__global__ __launch_bounds__(256, 2) void gemm_lse_k(
    const ushort* __restrict__ A, const ushort* __restrict__ W,
    const float* __restrict__ biasp, float* __restrict__ part_s,
    int n_chunks)
{
    __shared__ __align__(16) ushort lds[3 * 16 * 512];  // 48 KB: 3 x (A 8KB | B 8KB)
    int bid = blockIdx.x;
    int k = bid & 7, j = bid >> 3;
    int nb = k * 20 + (j >> 3);     // n-block 0..159, XCD-local stripe
    int mb = j & 7;                 // m-block 0..7
    int wave = threadIdx.x >> 6, lane = threadIdx.x & 63;
    int wr = wave >> 1, wc = wave & 1;
    int quad = lane >> 4, colid = lane & 15;

    f32x4 acc[4][4];
    #pragma unroll
    for (int mi = 0; mi < 4; ++mi)
        #pragma unroll
        for (int ni = 0; ni < 4; ++ni) acc[mi][ni] = (f32x4){0.f, 0.f, 0.f, 0.f};

    const long Abase = (long)mb * 8, Wbase = (long)nb * 8;

#define STAGE_K(ks, bf) do {                                                     \
        ushort* d_ = lds + (bf) * (16 * 512);                                    \
        _Pragma("unroll")                                                        \
        for (int i_ = 0; i_ < 2; ++i_) {                                         \
            int t_ = 2 * wave + i_;                                              \
            gld_lds16(A + ((Abase + t_) * KB + (ks)) * 512 + lane * 8,           \
                      d_ + t_ * 512 + lane * 8);                                 \
            gld_lds16(W + ((Wbase + t_) * KB + (ks)) * 512 + lane * 8,           \
                      d_ + (8 + t_) * 512 + lane * 8);                           \
        }                                                                        \
    } while (0)

#define COMP_K(bf) do {                                                          \
        const ushort* b_ = lds + (bf) * (16 * 512);                              \
        s16x8 af[4], bfg[4];                                                     \
        _Pragma("unroll")                                                        \
        for (int mi = 0; mi < 4; ++mi)                                           \
            af[mi] = *(const s16x8*)(b_ + (wr * 4 + mi) * 512 + lane * 8);       \
        _Pragma("unroll")                                                        \
        for (int ni = 0; ni < 4; ++ni)                                           \
            bfg[ni] = *(const s16x8*)(b_ + (8 + wc * 4 + ni) * 512 + lane * 8);  \
        _Pragma("unroll")                                                        \
        for (int mi = 0; mi < 4; ++mi)                                           \
            _Pragma("unroll")                                                    \
            for (int ni = 0; ni < 4; ++ni)                                       \
                acc[mi][ni] = mfma_bf16(af[mi], bfg[ni], acc[mi][ni]);           \
    } while (0)

    STAGE_K(0, 0);
    STAGE_K(1, 1);
    for (int g = 0; g < KB - 1; ++g) {
        asm volatile("s_waitcnt vmcnt(4)" ::: "memory");
        PIPE_BARRIER();
        if (g + 2 < KB) STAGE_K(g + 2, (g + 2) % 3);
        COMP_K(g % 3);
        asm volatile("s_waitcnt lgkmcnt(0)" ::: "memory");
        __builtin_amdgcn_sched_barrier(0);
    }
    asm volatile("s_waitcnt vmcnt(0)" ::: "memory");
    PIPE_BARRIER();
    COMP_K((KB - 1) % 3);
#undef STAGE_K
#undef COMP_K

    // epilogue: bias + exp2 + row-sum over this wave's 64 cols
    float bv[4];
    long c0 = (long)nb * 128 + wc * 64 + colid;
    #pragma unroll
    for (int ni = 0; ni < 4; ++ni) bv[ni] = biasp[c0 + ni * 16];
    int chunk = nb * 2 + wc;
    #pragma unroll
    for (int mi = 0; mi < 4; ++mi) {
        #pragma unroll
        for (int r = 0; r < 4; ++r) {
            float v = 0.f;
            #pragma unroll
            for (int ni = 0; ni < 4; ++ni)
                v += __builtin_amdgcn_exp2f(acc[mi][ni][r] + bv[ni]);
            v += __shfl_xor(v, 1);
            v += __shfl_xor(v, 2);
            v += __shfl_xor(v, 4);
            v += __shfl_xor(v, 8);
            if (colid == 0) {
                int m = mb * 128 + wr * 64 + mi * 16 + quad * 4 + r;
                part_s[(long)m * n_chunks + chunk] = v;
            }
        }
    }
}

// ============ gemm_lse_n: K=32, N-pipelined (tail2, tail3) =========
// r7: COMP materialized acc_[4][4] (64 VGPR) + 64-wide exp2 epilogue; adjacent
// tiles' chains overlapped -> live set >128 -> spill (351 MB scratch writes).
// Restructured: process the 4 n-fragments SEQUENTIALLY; peak live set ~60 regs.
// (256,3): 3 blocks/CU for the trans-unit-bound exp2 work (demand << budget).
__global__ __launch_bounds__(256, 3) void gemm_lse_n(
    const ushort* __restrict__ A, const ushort* __restrict__ W,
    const float* __restrict__ biasp, float* __restrict__ part_s,
    int n_chunks, int vng, int ngmax)
{
    __shared__ __align__(16) ushort ldsA[8 * 512];       // 8 KB
    __shared__ __align__(16) ushort ldsW[3 * 8 * 512];   // 24 KB
    __shared__ float ldsB[1024];                         // 4 KB
    int bid = blockIdx.x;
    int k = bid & 7, j = bid >> 3;
    int ng = k * vng + (j >> 3);
    int mb = j & 7;
    if (ng >= ngmax) return;
    int wave = threadIdx.x >> 6, lane = threadIdx.x & 63;
    int wr = wave >> 1, wc = wave & 1;
    int quad = lane >> 4, colid = lane & 15;

    // stage A once (contiguous: KB=1 -> block index == m_tile)
    #pragma unroll
    for (int i = 0; i < 2; ++i) {
        int t = 2 * wave + i;
        gld_lds16(A + ((long)(mb * 8 + t)) * 512 + lane * 8, ldsA + t * 512 + lane * 8);
    }
    // bias -> LDS
    for (int i = threadIdx.x; i < 1024; i += 256) ldsB[i] = biasp[(long)ng * 1024 + i];
    __syncthreads();   // full drain: vmcnt back to 0, A + bias visible

    s16x8 af[4];
    #pragma unroll
    for (int mi = 0; mi < 4; ++mi)
        af[mi] = *(const s16x8*)(ldsA + (wr * 4 + mi) * 512 + lane * 8);

    float s_acc[4][4];
    #pragma unroll
    for (int mi = 0; mi < 4; ++mi)
        #pragma unroll
        for (int r = 0; r < 4; ++r) s_acc[mi][r] = 0.f;

    const long Wg = (long)ng * 64;

#define STAGE_N(t, bf) do {                                                      \
        ushort* d_ = ldsW + (bf) * (8 * 512);                                    \
        _Pragma("unroll")                                                        \
        for (int i_ = 0; i_ < 2; ++i_) {                                         \
            int b_ = 2 * wave + i_;                                              \
            gld_lds16(W + (Wg + (t) * 8 + b_) * 512 + lane * 8,                  \
                      d_ + b_ * 512 + lane * 8);                                 \
        }                                                                        \
    } while (0)

// Sequential n-fragments: per ni only 4 f32x4 accs live (16 regs).
#define COMP_N(t, bf) do {                                                       \
        const ushort* wb_ = ldsW + (bf) * (8 * 512);                             \
        _Pragma("unroll")                                                        \
        for (int ni = 0; ni < 4; ++ni) {                                         \
            s16x8 bfg = *(const s16x8*)(wb_ + (wc * 4 + ni) * 512 + lane * 8);   \
            float bv = ldsB[(t) * 128 + wc * 64 + ni * 16 + colid];              \
            f32x4 a0 = {bv, bv, bv, bv};                                         \
            f32x4 a1 = {bv, bv, bv, bv};                                         \
            f32x4 a2 = {bv, bv, bv, bv};                                         \
            f32x4 a3 = {bv, bv, bv, bv};                                         \
            a0 = mfma_bf16(af[0], bfg, a0);                                      \
            a1 = mfma_bf16(af[1], bfg, a1);                                      \
            a2 = mfma_bf16(af[2], bfg, a2);                                      \
            a3 = mfma_bf16(af[3], bfg, a3);                                      \
            _Pragma("unroll")                                                    \
            for (int r = 0; r < 4; ++r) {                                        \
                s_acc[0][r] += __builtin_amdgcn_exp2f(a0[r]);                    \
                s_acc[1][r] += __builtin_amdgcn_exp2f(a1[r]);                    \
                s_acc[2][r] += __builtin_amdgcn_exp2f(a2[r]);                    \
                s_acc[3][r] += __builtin_amdgcn_exp2f(a3[r]);                    \
            }                                                                    \
        }                                                                        \
    } while (0)

    STAGE_N(0, 0);
    STAGE_N(1, 1);
    for (int t = 0; t < 7; ++t) {
        asm volatile("s_waitcnt vmcnt(2)" ::: "memory");
        PIPE_BARRIER();
        if (t + 2 < 8) STAGE_N(t + 2, (t + 2) % 3);
        COMP_N(t, t % 3);
        asm volatile("s_waitcnt lgkmcnt(0)" ::: "memory");
        __builtin_amdgcn_sched_barrier(0);
    }
    asm volatile("s_waitcnt vmcnt(0)" ::: "memory");
    PIPE_BARRIER();
    COMP_N(7, 7 % 3);
#undef STAGE_N
#undef COMP_N

    int chunk = ng * 2 + wc;
    #pragma unroll
    for (int mi = 0; mi < 4; ++mi)
        #pragma unroll
        for (int r = 0; r < 4; ++r) {
            float v = s_acc[mi][r];
            v += __shfl_xor(v, 1);
            v += __shfl_xor(v, 2);
            v += __shfl_xor(v, 4);
            v += __shfl_xor(v, 8);
            if (colid == 0) {
                int m = mb * 128 + wr * 64 + mi * 16 + quad * 4 + r;
                part_s[(long)m * n_chunks + chunk] = v;
            }
        }
}

// ---------------- finalize ----------------
__device__ __forceinline__ float swz_dot(const ushort* __restrict__ H, int m,
                                         const ushort* __restrict__ Wm, long vrow,
                                         int K, int lane)
{
    float d = 0.f;
    if (lane * 8 < K) {
        int ks = lane >> 2, q = lane & 3;
        int KB = K >> 5;
        const ushort* hp = H + ((long)(m >> 4) * KB + ks) * 512 + (q * 16 + (m & 15)) * 8;
        const ushort* wp = Wm + ((vrow >> 4) * KB + ks) * 512 + (q * 16 + (int)(vrow & 15)) * 8;
        #pragma unroll
        for (int j = 0; j < 8; ++j) d += bf2f(hp[j]) * bf2f(wp[j]);
    }
    d += __shfl_xor(d, 1);  d += __shfl_xor(d, 2);  d += __shfl_xor(d, 4);
    d += __shfl_xor(d, 8);  d += __shfl_xor(d, 16); d += __shfl_xor(d, 32);
    return d;
}

__global__ __launch_bounds__(256) void finalize_kernel(
    const int* __restrict__ target,
    const ushort* __restrict__ H0, const ushort* __restrict__ hw,
    const float* __restrict__ hbp, const float* __restrict__ sH,
    const ushort* __restrict__ H1, const ushort* __restrict__ w1,
    const float* __restrict__ b1p, const float* __restrict__ s1,
    const ushort* __restrict__ H2, const ushort* __restrict__ w2,
    const float* __restrict__ b2p, const float* __restrict__ s2,
    const ushort* __restrict__ H3, const ushort* __restrict__ w3,
    const float* __restrict__ b3p, const float* __restrict__ s3,
    float* __restrict__ out)
{
    int wave = threadIdx.x >> 6, lane = threadIdx.x & 63;
    int m = blockIdx.x * 4 + wave;
    int t = target[m];
    int cid = (t >= 20000) + (t >= 40000) + (t >= 200000);

    float s = 0.f;
    for (int i = lane; i < NCHK_H; i += 64) s += sH[(long)m * NCHK_H + i];
    s += __shfl_xor(s, 1);  s += __shfl_xor(s, 2);  s += __shfl_xor(s, 4);
    s += __shfl_xor(s, 8);  s += __shfl_xor(s, 16); s += __shfl_xor(s, 32);
    float lse_h = __logf(s);

    int hc = (cid == 0) ? t : (20003 - cid);
    float d = swz_dot(H0, m, hw, hc, 512, lane);          // scaled by LOG2E
    float nll = lse_h - (d + hbp[hc]) * LN2F;

    if (cid > 0) {
        const ushort *Hi, *Wi; const float *bi, *si; int K, nc, l;
        if (cid == 1)      { Hi = H1; Wi = w1; bi = b1p; si = s1; K = 128; nc = NCHK_1; l = 20000; }
        else if (cid == 2) { Hi = H2; Wi = w2; bi = b2p; si = s2; K = 32;  nc = NCHK_2; l = 40000; }
        else               { Hi = H3; Wi = w3; bi = b3p; si = s3; K = 32;  nc = NCHK_3; l = 200000; }
        int rel = t - l;
        float ts = 0.f;
        for (int i = lane; i < nc; i += 64) ts += si[(long)m * nc + i];
        ts += __shfl_xor(ts, 1);  ts += __shfl_xor(ts, 2);  ts += __shfl_xor(ts, 4);
        ts += __shfl_xor(ts, 8);  ts += __shfl_xor(ts, 16); ts += __shfl_xor(ts, 32);
        float lse_t = __logf(ts);
        float dt = swz_dot(Hi, m, Wi, rel, K, lane);      // scaled by LOG2E
        nll += lse_t - (dt + bi[rel]) * LN2F;
    }
    if (lane == 0) out[m] = nll;
}

// ---------------- host ----------------
extern "C" void kernel_launch(void* const* d_in, const int* in_sizes, int n_in,
                              void* d_out, int out_size, void* d_ws, size_t ws_size,
                              hipStream_t stream) {
    const float* hidden = (const float*)d_in[0];
    const int*   target = (const int*)d_in[1];
    const float* W0 = (const float*)d_in[2];
    const float* b0 = (const float*)d_in[3];
    const float* p0 = (const float*)d_in[4];
    const float* W1 = (const float*)d_in[5];
    const float* b1 = (const float*)d_in[6];
    const float* p1 = (const float*)d_in[7];
    const float* W2 = (const float*)d_in[8];
    const float* b2 = (const float*)d_in[9];
    const float* p2 = (const float*)d_in[10];
    const float* W3 = (const float*)d_in[11];
    const float* b3 = (const float*)d_in[12];
    const float* p3 = (const float*)d_in[13];
    const float* cw = (const float*)d_in[14];
    const float* cb = (const float*)d_in[15];

    char* ws = (char*)d_ws;
    ushort* hw  = (ushort*)(ws + OFF_HW);
    ushort* ow1 = (ushort*)(ws + OFF_W1);
    ushort* ow2 = (ushort*)(ws + OFF_W2);
    ushort* ow3 = (ushort*)(ws + OFF_W3);
    ushort* hid = (ushort*)(ws + OFF_HID);
    ushort* pT0 = (ushort*)(ws + OFF_PT0);
    ushort* pT1 = (ushort*)(ws + OFF_PT1);
    ushort* pT2 = (ushort*)(ws + OFF_PT2);
    ushort* pT3 = (ushort*)(ws + OFF_PT3);
    ushort* H0  = (ushort*)(ws + OFF_H0);
    ushort* H1  = (ushort*)(ws + OFF_H1);
    ushort* H2  = (ushort*)(ws + OFF_H2);
    ushort* H3  = (ushort*)(ws + OFF_H3);
    float* hbp = (float*)(ws + OFF_HB);
    float* b1p = (float*)(ws + OFF_B1);
    float* b2p = (float*)(ws + OFF_B2);
    float* b3p = (float*)(ws + OFF_B3);
    float* sH  = (float*)(ws + OFF_SH);
    float* s1  = (float*)(ws + OFF_S1);
    float* s2  = (float*)(ws + OFF_S2);
    float* s3  = (float*)(ws + OFF_S3);

    prep_wswz<<<10464, 256, 0, stream>>>(hidden, W0, cw, W1, W2, W3,
                                         p0, p1, p2, p3,
                                         hw, ow1, ow2, ow3, hid, pT0, pT1, pT2, pT3);
    prep_bias<<<1072, 256, 0, stream>>>(b0, b1, b2, b3, cb, hbp, b1p, b2p, b3p);

    gemm_all<<<dim3(NTOK / 64, 44), 256, 0, stream>>>(hid, pT0, pT1, pT2, pT3,
                                                      H0, H1, H2, H3);

    // head: 8 m-blocks x 160 n-blocks
    gemm_lse_k<16><<<1280, 256, 0, stream>>>(H0, hw, hbp, sH, NCHK_H);
    // tail1: K=128
    gemm_lse_k<4><<<1280, 256, 0, stream>>>(H1, ow1, b1p, s1, NCHK_1);
    // tail2: 160 n-groups of 1024 cols
    gemm_lse_n<<<1280, 256, 0, stream>>>(H2, ow2, b2p, s2, NCHK_2, 20, 160);
    // tail3: 67 n-groups (virtual 72)
    gemm_lse_n<<<576, 256, 0, stream>>>(H3, ow3, b3p, s3, NCHK_3, 9, 67);

    finalize_kernel<<<NTOK / 4, 256, 0, stream>>>(target,
        H0, hw, hbp, sH, H1, ow1, b1p, s1, H2, ow2, b2p, s2, H3, ow3, b3p, s3,
        (float*)d_out);
}

// Round 9
// 508.903 us; speedup vs baseline: 1.1029x; 1.1029x over previous
//
#include <hip/hip_runtime.h>

typedef short s16x8 __attribute__((ext_vector_type(8)));
typedef unsigned short u16x8 __attribute__((ext_vector_type(8)));
typedef float f32x4 __attribute__((ext_vector_type(4)));
typedef unsigned short ushort;

// ---------------- problem constants ----------------
#define NTOK 1024
#define DHID 512

#define VH   20003
#define KH   512
#define VH_PAD 20480

#define V1   20000
#define K1   128
#define V1_PAD 20480

#define V2   160000
#define K2   32
#define V2_PAD 163840

#define V3   67735
#define K3   32
#define V3_PAD 68608

// partial-sum chunk counts (see gemm_lse_* epilogues)
#define NCHK_H 320     // 160 n-blocks x 2 col-halves
#define NCHK_1 320
#define NCHK_2 320     // 160 n-groups x 2
#define NCHK_3 134     // 67 n-groups x 2

#define PAD_BIAS (-1e30f)
#define LOG2E 1.4426950408889634f
#define LN2F  0.6931471805599453f

// Pipeline barrier that is ALSO a compiler fence (r6 inf bug: raw
// __builtin_amdgcn_s_barrier is not an LLVM memory fence; ds_reads were
// hoisted above it and raced other waves' in-flight global_load_lds).
#define PIPE_BARRIER() do {                                   \
        asm volatile("s_barrier" ::: "memory");               \
        __builtin_amdgcn_sched_barrier(0);                    \
    } while (0)

// ---------------- ws layout (bytes) ----------------
#define OFF_HW   0UL
#define OFF_W1   (OFF_HW  + (unsigned long)VH_PAD*KH*2)
#define OFF_W2   (OFF_W1  + (unsigned long)V1_PAD*K1*2)
#define OFF_W3   (OFF_W2  + (unsigned long)V2_PAD*K2*2)
#define OFF_HID  (OFF_W3  + (unsigned long)V3_PAD*K3*2)
#define OFF_PT0  (OFF_HID + (unsigned long)NTOK*DHID*2)
#define OFF_PT1  (OFF_PT0 + (unsigned long)512*DHID*2)
#define OFF_PT2  (OFF_PT1 + (unsigned long)128*DHID*2)
#define OFF_PT3  (OFF_PT2 + (unsigned long)32*DHID*2)
#define OFF_H0   (OFF_PT3 + (unsigned long)32*DHID*2)
#define OFF_H1   (OFF_H0  + (unsigned long)NTOK*512*2)
#define OFF_H2   (OFF_H1  + (unsigned long)NTOK*128*2)
#define OFF_H3   (OFF_H2  + (unsigned long)NTOK*32*2)
#define OFF_HB   (OFF_H3  + (unsigned long)NTOK*32*2)
#define OFF_B1   (OFF_HB  + (unsigned long)VH_PAD*4)
#define OFF_B2   (OFF_B1  + (unsigned long)V1_PAD*4)
#define OFF_B3   (OFF_B2  + (unsigned long)V2_PAD*4)
#define OFF_SH   (OFF_B3  + (unsigned long)V3_PAD*4)
#define OFF_S1   (OFF_SH  + (unsigned long)NTOK*NCHK_H*4)
#define OFF_S2   (OFF_S1  + (unsigned long)NTOK*NCHK_1*4)
#define OFF_S3   (OFF_S2  + (unsigned long)NTOK*NCHK_2*4)

// ---------------- helpers ----------------
__device__ __forceinline__ ushort f2bf(float f) {
    union { float f; unsigned u; } x; x.f = f;
    unsigned r = x.u + 0x7fffu + ((x.u >> 16) & 1u);
    return (ushort)(r >> 16);
}
__device__ __forceinline__ float bf2f(ushort h) {
    union { unsigned u; float f; } x; x.u = ((unsigned)h) << 16;
    return x.f;
}
__device__ __forceinline__ f32x4 mfma_bf16(s16x8 a, s16x8 b, f32x4 c) {
    return __builtin_amdgcn_mfma_f32_16x16x32_bf16(a, b, c, 0, 0, 0);
}
__device__ __forceinline__ void ld8(const float* p, float* v) {
    float4 a = *(const float4*)p, b = *(const float4*)(p + 4);
    v[0]=a.x; v[1]=a.y; v[2]=a.z; v[3]=a.w; v[4]=b.x; v[5]=b.y; v[6]=b.z; v[7]=b.w;
}
__device__ __forceinline__ void gld_lds16(const ushort* g, ushort* l) {
    __builtin_amdgcn_global_load_lds(
        (const __attribute__((address_space(1))) unsigned int*)g,
        (__attribute__((address_space(3))) unsigned int*)l, 16, 0, 0);
}

// ---------------- prep: wave-per-512-element-block swizzle ----------------
// W arrays pre-scaled by LOG2E so fused kernels use exp2; finalize scales by LN2.
#define WB_HW  20480L
#define WB_W1  5120L
#define WB_W2  10240L
#define WB_W3  4288L
#define WB_HID 1024L
#define WB_PT0 512L
#define WB_PT1 128L
#define WB_PT2 32L
#define WB_PT3 32L
#define WB_TOTAL (WB_HW+WB_W1+WB_W2+WB_W3+WB_HID+WB_PT0+WB_PT1+WB_PT2+WB_PT3)

__global__ __launch_bounds__(256) void prep_wswz(
    const float* __restrict__ hidden,
    const float* __restrict__ W0, const float* __restrict__ cw,
    const float* __restrict__ W1, const float* __restrict__ W2, const float* __restrict__ W3,
    const float* __restrict__ p0, const float* __restrict__ p1,
    const float* __restrict__ p2, const float* __restrict__ p3,
    ushort* __restrict__ hw, ushort* __restrict__ ow1,
    ushort* __restrict__ ow2, ushort* __restrict__ ow3,
    ushort* __restrict__ hid,
    ushort* __restrict__ pT0, ushort* __restrict__ pT1,
    ushort* __restrict__ pT2, ushort* __restrict__ pT3)
{
    int lane = threadIdx.x & 63;
    int r = lane & 15, quad = lane >> 4;
    long wb0 = (long)blockIdx.x * 4 + (threadIdx.x >> 6);
    long nw = (long)gridDim.x * 4;
    for (long wb = wb0; wb < WB_TOTAL; wb += nw) {
        long b = wb;
        float vals[8];
        #pragma unroll
        for (int j = 0; j < 8; ++j) vals[j] = 0.f;
        float scale = LOG2E;
        ushort* dst;
        if (b < WB_HW) {
            long tile = b >> 4, ks = b & 15;
            long v = tile * 16 + r, k = ks * 32 + quad * 8;
            if (v < 20000)      ld8(W0 + v * 512 + k, vals);
            else if (v < VH)    ld8(cw + (v - 20000) * 512 + k, vals);
            dst = hw + b * 512 + (long)lane * 8;
        } else if ((b -= WB_HW) < WB_W1) {
            long tile = b >> 2, ks = b & 3;
            long v = tile * 16 + r, k = ks * 32 + quad * 8;
            if (v < V1) ld8(W1 + v * 128 + k, vals);
            dst = ow1 + b * 512 + (long)lane * 8;
        } else if ((b -= WB_W1) < WB_W2) {
            long v = b * 16 + r;
            if (v < V2) ld8(W2 + v * 32 + quad * 8, vals);
            dst = ow2 + b * 512 + (long)lane * 8;
        } else if ((b -= WB_W2) < WB_W3) {
            long v = b * 16 + r;
            if (v < V3 && quad == 0) ld8(W3 + v * 8, vals);
            dst = ow3 + b * 512 + (long)lane * 8;
        } else if ((b -= WB_W3) < WB_HID) {
            scale = 1.f;
            long tile = b >> 4, ks = b & 15;
            long v = tile * 16 + r, k = ks * 32 + quad * 8;
            ld8(hidden + v * 512 + k, vals);
            dst = hid + b * 512 + (long)lane * 8;
        } else if ((b -= WB_HID) < WB_PT0) {
            scale = 1.f;
            long tile = b >> 4, ks = b & 15;
            long c = tile * 16 + r, k = ks * 32 + quad * 8;
            #pragma unroll
            for (int j = 0; j < 8; ++j) vals[j] = p0[(k + j) * 512 + c];
            dst = pT0 + b * 512 + (long)lane * 8;
        } else if ((b -= WB_PT0) < WB_PT1) {
            scale = 1.f;
            long tile = b >> 4, ks = b & 15;
            long c = tile * 16 + r, k = ks * 32 + quad * 8;
            #pragma unroll
            for (int j = 0; j < 8; ++j) vals[j] = p1[(k + j) * 128 + c];
            dst = pT1 + b * 512 + (long)lane * 8;
        } else if ((b -= WB_PT1) < WB_PT2) {
            scale = 1.f;
            long tile = b >> 4, ks = b & 15;
            long c = tile * 16 + r, k = ks * 32 + quad * 8;
            #pragma unroll
            for (int j = 0; j < 8; ++j) vals[j] = p2[(k + j) * 32 + c];
            dst = pT2 + b * 512 + (long)lane * 8;
        } else {
            scale = 1.f;
            b -= WB_PT2;
            long tile = b >> 4, ks = b & 15;
            long c = tile * 16 + r, k = ks * 32 + quad * 8;
            if (c < 8) {
                #pragma unroll
                for (int j = 0; j < 8; ++j) vals[j] = p3[(k + j) * 8 + c];
            }
            dst = pT3 + b * 512 + (long)lane * 8;
        }
        u16x8 o;
        #pragma unroll
        for (int j = 0; j < 8; ++j) o[j] = f2bf(vals[j] * scale);
        *(u16x8*)dst = o;
    }
}

// ---------------- prep: padded biases (pre-scaled by LOG2E) ----------------
#define E_HB  ((long)VH_PAD)
#define E_B1  ((long)V1_PAD)
#define E_B2  ((long)V2_PAD)
#define E_B3  ((long)V3_PAD)
#define E_BIAS (E_HB+E_B1+E_B2+E_B3)

__global__ __launch_bounds__(256) void prep_bias(
    const float* __restrict__ b0, const float* __restrict__ b1,
    const float* __restrict__ b2, const float* __restrict__ b3,
    const float* __restrict__ cb,
    float* __restrict__ hbp, float* __restrict__ ob1,
    float* __restrict__ ob2, float* __restrict__ ob3)
{
    long stride = (long)gridDim.x * blockDim.x;
    for (long i = (long)blockIdx.x * blockDim.x + threadIdx.x; i < E_BIAS; i += stride) {
        long j = i;
        if (j < E_HB) {
            hbp[j] = ((j < 20000) ? b0[j] : (j < VH) ? cb[j - 20000] : PAD_BIAS) * LOG2E;
        } else if ((j -= E_HB) < E_B1) {
            ob1[j] = ((j < V1) ? b1[j] : PAD_BIAS) * LOG2E;
        } else if ((j -= E_B1) < E_B2) {
            ob2[j] = ((j < V2) ? b2[j] : PAD_BIAS) * LOG2E;
        } else { j -= E_B2;
            ob3[j] = ((j < V3) ? b3[j] : PAD_BIAS) * LOG2E;
        }
    }
}

// ---------------- gemm_h body + merged launch ----------------
__device__ __forceinline__ void gemm_body(
    const ushort* __restrict__ A, const ushort* __restrict__ Bt,
    ushort* __restrict__ Hout, int dpad, int c_tile)
{
    int wave = threadIdx.x >> 6, lane = threadIdx.x & 63;
    int quad = lane >> 4, colid = lane & 15;
    int m_tile = blockIdx.x * 4 + wave;
    const ushort* Ab = A + ((long)m_tile * 16) * 512 + lane * 8;
    const ushort* Bb = Bt + ((long)c_tile * 16) * 512 + lane * 8;
    f32x4 acc = {0.f, 0.f, 0.f, 0.f};
    #pragma unroll
    for (int ks = 0; ks < 16; ++ks) {
        s16x8 a = *(const s16x8*)(Ab + ks * 512);
        s16x8 b = *(const s16x8*)(Bb + ks * 512);
        acc = mfma_bf16(a, b, acc);
    }
    int KBo = dpad >> 5;
    int col = c_tile * 16 + colid;
    int ks_o = col >> 5, q_o = (col >> 3) & 3, j_o = col & 7;
    #pragma unroll
    for (int r = 0; r < 4; ++r) {
        int rm = quad * 4 + r;
        Hout[((long)m_tile * KBo + ks_o) * 512 + (q_o * 16 + rm) * 8 + j_o] = f2bf(acc[r]);
    }
}

__global__ __launch_bounds__(256) void gemm_all(
    const ushort* __restrict__ hid,
    const ushort* __restrict__ pT0, const ushort* __restrict__ pT1,
    const ushort* __restrict__ pT2, const ushort* __restrict__ pT3,
    ushort* __restrict__ H0, ushort* __restrict__ H1,
    ushort* __restrict__ H2, ushort* __restrict__ H3)
{
    int y = blockIdx.y;
    if (y < 32)      gemm_body(hid, pT0, H0, 512, y);
    else if (y < 40) gemm_body(hid, pT1, H1, 128, y - 32);
    else if (y < 42) gemm_body(hid, pT2, H2, 32,  y - 40);
    else             gemm_body(hid, pT3, H3, 32,  y - 42);
}

// ============ gemm_lse_k: 128x128 tile, K-pipelined (head KB=16, tail1 KB=4) =========
// (256,2) + fenced barriers. COMP keeps bfg[4] resident and loads af PER-mi
// (4 transient regs instead of 16) -> peak ~105 < 128-reg cap, regalloc slack.
template<int KB>
__global__ __launch_bounds__(256, 2) void gemm_lse_k(
    const ushort* __restrict__ A, const ushort* __restrict__ W,
    const float* __restrict__ biasp, float* __restrict__ part_s,
    int n_chunks)
{
    __shared__ __align__(16) ushort lds[3 * 16 * 512];  // 48 KB: 3 x (A 8KB | B 8KB)
    int bid = blockIdx.x;
    int k = bid & 7, j = bid >> 3;
    int nb = k * 20 + (j >> 3);     // n-block 0..159, XCD-local stripe
    int mb = j & 7;                 // m-block 0..7
    int wave = threadIdx.x >> 6, lane = threadIdx.x & 63;
    int wr = wave >> 1, wc = wave & 1;
    int quad = lane >> 4, colid = lane & 15;

    f32x4 acc[4][4];
    #pragma unroll
    for (int mi = 0; mi < 4; ++mi)
        #pragma unroll
        for (int ni = 0; ni < 4; ++ni) acc[mi][ni] = (f32x4){0.f, 0.f, 0.f, 0.f};

    const long Abase = (long)mb * 8, Wbase = (long)nb * 8;

#define STAGE_K(ks, bf) do {                                                     \
        ushort* d_ = lds + (bf) * (16 * 512);                                    \
        _Pragma("unroll")                                                        \
        for (int i_ = 0; i_ < 2; ++i_) {                                         \
            int t_ = 2 * wave + i_;                                              \
            gld_lds16(A + ((Abase + t_) * KB + (ks)) * 512 + lane * 8,           \
                      d_ + t_ * 512 + lane * 8);                                 \
            gld_lds16(W + ((Wbase + t_) * KB + (ks)) * 512 + lane * 8,           \
                      d_ + (8 + t_) * 512 + lane * 8);                           \
        }                                                                        \
    } while (0)

#define COMP_K(bf) do {                                                          \
        const ushort* b_ = lds + (bf) * (16 * 512);                              \
        s16x8 bfg[4];                                                            \
        _Pragma("unroll")                                                        \
        for (int ni = 0; ni < 4; ++ni)                                           \
            bfg[ni] = *(const s16x8*)(b_ + (8 + wc * 4 + ni) * 512 + lane * 8);  \
        _Pragma("unroll")                                                        \
        for (int mi = 0; mi < 4; ++mi) {                                         \
            s16x8 af = *(const s16x8*)(b_ + (wr * 4 + mi) * 512 + lane * 8);     \
            _Pragma("unroll")                                                    \
            for (int ni = 0; ni < 4; ++ni)                                       \
                acc[mi][ni] = mfma_bf16(af, bfg[ni], acc[mi][ni]);               \
        }                                                                        \
    } while (0)

    STAGE_K(0, 0);
    STAGE_K(1, 1);
    for (int g = 0; g < KB - 1; ++g) {
        asm volatile("s_waitcnt vmcnt(4)" ::: "memory");
        PIPE_BARRIER();
        if (g + 2 < KB) STAGE_K(g + 2, (g + 2) % 3);
        COMP_K(g % 3);
        asm volatile("s_waitcnt lgkmcnt(0)" ::: "memory");
        __builtin_amdgcn_sched_barrier(0);
    }
    asm volatile("s_waitcnt vmcnt(0)" ::: "memory");
    PIPE_BARRIER();
    COMP_K((KB - 1) % 3);
#undef STAGE_K
#undef COMP_K

    // epilogue: bias + exp2 + row-sum over this wave's 64 cols
    float bv[4];
    long c0 = (long)nb * 128 + wc * 64 + colid;
    #pragma unroll
    for (int ni = 0; ni < 4; ++ni) bv[ni] = biasp[c0 + ni * 16];
    int chunk = nb * 2 + wc;
    #pragma unroll
    for (int mi = 0; mi < 4; ++mi) {
        #pragma unroll
        for (int r = 0; r < 4; ++r) {
            float v = 0.f;
            #pragma unroll
            for (int ni = 0; ni < 4; ++ni)
                v += __builtin_amdgcn_exp2f(acc[mi][ni][r] + bv[ni]);
            v += __shfl_xor(v, 1);
            v += __shfl_xor(v, 2);
            v += __shfl_xor(v, 4);
            v += __shfl_xor(v, 8);
            if (colid == 0) {
                int m = mb * 128 + wr * 64 + mi * 16 + quad * 4 + r;
                part_s[(long)m * n_chunks + chunk] = v;
            }
        }
    }
}

// ============ gemm_lse_n: K=32, N-pipelined (tail2, tail3) =========
// r7/r8 lesson: source-level sequencing does NOT bound the live set — the
// scheduler hoisted all 4 ni-iterations' MFMAs above the exp2s (latency
// hiding), recreating 64+ live accs -> spill at any budget (351/454 MB
// scratch). Fix: sched_barrier(0) AFTER EACH ni iteration — the scheduler
// cannot merge iterations, peak live ~70 regs < the 84-reg (256,3) cap.
__global__ __launch_bounds__(256, 3) void gemm_lse_n(
    const ushort* __restrict__ A, const ushort* __restrict__ W,
    const float* __restrict__ biasp, float* __restrict__ part_s,
    int n_chunks, int vng, int ngmax)
{
    __shared__ __align__(16) ushort ldsA[8 * 512];       // 8 KB
    __shared__ __align__(16) ushort ldsW[3 * 8 * 512];   // 24 KB
    __shared__ float ldsB[1024];                         // 4 KB
    int bid = blockIdx.x;
    int k = bid & 7, j = bid >> 3;
    int ng = k * vng + (j >> 3);
    int mb = j & 7;
    if (ng >= ngmax) return;
    int wave = threadIdx.x >> 6, lane = threadIdx.x & 63;
    int wr = wave >> 1, wc = wave & 1;
    int quad = lane >> 4, colid = lane & 15;

    // stage A once (contiguous: KB=1 -> block index == m_tile)
    #pragma unroll
    for (int i = 0; i < 2; ++i) {
        int t = 2 * wave + i;
        gld_lds16(A + ((long)(mb * 8 + t)) * 512 + lane * 8, ldsA + t * 512 + lane * 8);
    }
    // bias -> LDS
    for (int i = threadIdx.x; i < 1024; i += 256) ldsB[i] = biasp[(long)ng * 1024 + i];
    __syncthreads();   // full drain: vmcnt back to 0, A + bias visible

    s16x8 af[4];
    #pragma unroll
    for (int mi = 0; mi < 4; ++mi)
        af[mi] = *(const s16x8*)(ldsA + (wr * 4 + mi) * 512 + lane * 8);

    float s_acc[4][4];
    #pragma unroll
    for (int mi = 0; mi < 4; ++mi)
        #pragma unroll
        for (int r = 0; r < 4; ++r) s_acc[mi][r] = 0.f;

    const long Wg = (long)ng * 64;

#define STAGE_N(t, bf) do {                                                      \
        ushort* d_ = ldsW + (bf) * (8 * 512);                                    \
        _Pragma("unroll")                                                        \
        for (int i_ = 0; i_ < 2; ++i_) {                                         \
            int b_ = 2 * wave + i_;                                              \
            gld_lds16(W + (Wg + (t) * 8 + b_) * 512 + lane * 8,                  \
                      d_ + b_ * 512 + lane * 8);                                 \
        }                                                                        \
    } while (0)

// Per-ni sched_barrier: the live-range bound is ENFORCED, not hoped for.
#define COMP_N(t, bf) do {                                                       \
        const ushort* wb_ = ldsW + (bf) * (8 * 512);                             \
        _Pragma("unroll")                                                        \
        for (int ni = 0; ni < 4; ++ni) {                                         \
            s16x8 bfg = *(const s16x8*)(wb_ + (wc * 4 + ni) * 512 + lane * 8);   \
            float bv = ldsB[(t) * 128 + wc * 64 + ni * 16 + colid];              \
            f32x4 a0 = {bv, bv, bv, bv};                                         \
            f32x4 a1 = {bv, bv, bv, bv};                                         \
            f32x4 a2 = {bv, bv, bv, bv};                                         \
            f32x4 a3 = {bv, bv, bv, bv};                                         \
            a0 = mfma_bf16(af[0], bfg, a0);                                      \
            a1 = mfma_bf16(af[1], bfg, a1);                                      \
            a2 = mfma_bf16(af[2], bfg, a2);                                      \
            a3 = mfma_bf16(af[3], bfg, a3);                                      \
            _Pragma("unroll")                                                    \
            for (int r = 0; r < 4; ++r) {                                        \
                s_acc[0][r] += __builtin_amdgcn_exp2f(a0[r]);                    \
                s_acc[1][r] += __builtin_amdgcn_exp2f(a1[r]);                    \
                s_acc[2][r] += __builtin_amdgcn_exp2f(a2[r]);                    \
                s_acc[3][r] += __builtin_amdgcn_exp2f(a3[r]);                    \
            }                                                                    \
            __builtin_amdgcn_sched_barrier(0);                                   \
        }                                                                        \
    } while (0)

    STAGE_N(0, 0);
    STAGE_N(1, 1);
    for (int t = 0; t < 7; ++t) {
        asm volatile("s_waitcnt vmcnt(2)" ::: "memory");
        PIPE_BARRIER();
        if (t + 2 < 8) STAGE_N(t + 2, (t + 2) % 3);
        COMP_N(t, t % 3);
        asm volatile("s_waitcnt lgkmcnt(0)" ::: "memory");
        __builtin_amdgcn_sched_barrier(0);
    }
    asm volatile("s_waitcnt vmcnt(0)" ::: "memory");
    PIPE_BARRIER();
    COMP_N(7, 7 % 3);
#undef STAGE_N
#undef COMP_N

    int chunk = ng * 2 + wc;
    #pragma unroll
    for (int mi = 0; mi < 4; ++mi)
        #pragma unroll
        for (int r = 0; r < 4; ++r) {
            float v = s_acc[mi][r];
            v += __shfl_xor(v, 1);
            v += __shfl_xor(v, 2);
            v += __shfl_xor(v, 4);
            v += __shfl_xor(v, 8);
            if (colid == 0) {
                int m = mb * 128 + wr * 64 + mi * 16 + quad * 4 + r;
                part_s[(long)m * n_chunks + chunk] = v;
            }
        }
}

// ---------------- finalize ----------------
__device__ __forceinline__ float swz_dot(const ushort* __restrict__ H, int m,
                                         const ushort* __restrict__ Wm, long vrow,
                                         int K, int lane)
{
    float d = 0.f;
    if (lane * 8 < K) {
        int ks = lane >> 2, q = lane & 3;
        int KB = K >> 5;
        const ushort* hp = H + ((long)(m >> 4) * KB + ks) * 512 + (q * 16 + (m & 15)) * 8;
        const ushort* wp = Wm + ((vrow >> 4) * KB + ks) * 512 + (q * 16 + (int)(vrow & 15)) * 8;
        #pragma unroll
        for (int j = 0; j < 8; ++j) d += bf2f(hp[j]) * bf2f(wp[j]);
    }
    d += __shfl_xor(d, 1);  d += __shfl_xor(d, 2);  d += __shfl_xor(d, 4);
    d += __shfl_xor(d, 8);  d += __shfl_xor(d, 16); d += __shfl_xor(d, 32);
    return d;
}

__global__ __launch_bounds__(256) void finalize_kernel(
    const int* __restrict__ target,
    const ushort* __restrict__ H0, const ushort* __restrict__ hw,
    const float* __restrict__ hbp, const float* __restrict__ sH,
    const ushort* __restrict__ H1, const ushort* __restrict__ w1,
    const float* __restrict__ b1p, const float* __restrict__ s1,
    const ushort* __restrict__ H2, const ushort* __restrict__ w2,
    const float* __restrict__ b2p, const float* __restrict__ s2,
    const ushort* __restrict__ H3, const ushort* __restrict__ w3,
    const float* __restrict__ b3p, const float* __restrict__ s3,
    float* __restrict__ out)
{
    int wave = threadIdx.x >> 6, lane = threadIdx.x & 63;
    int m = blockIdx.x * 4 + wave;
    int t = target[m];
    int cid = (t >= 20000) + (t >= 40000) + (t >= 200000);

    float s = 0.f;
    for (int i = lane; i < NCHK_H; i += 64) s += sH[(long)m * NCHK_H + i];
    s += __shfl_xor(s, 1);  s += __shfl_xor(s, 2);  s += __shfl_xor(s, 4);
    s += __shfl_xor(s, 8);  s += __shfl_xor(s, 16); s += __shfl_xor(s, 32);
    float lse_h = __logf(s);

    int hc = (cid == 0) ? t : (20003 - cid);
    float d = swz_dot(H0, m, hw, hc, 512, lane);          // scaled by LOG2E
    float nll = lse_h - (d + hbp[hc]) * LN2F;

    if (cid > 0) {
        const ushort *Hi, *Wi; const float *bi, *si; int K, nc, l;
        if (cid == 1)      { Hi = H1; Wi = w1; bi = b1p; si = s1; K = 128; nc = NCHK_1; l = 20000; }
        else if (cid == 2) { Hi = H2; Wi = w2; bi = b2p; si = s2; K = 32;  nc = NCHK_2; l = 40000; }
        else               { Hi = H3; Wi = w3; bi = b3p; si = s3; K = 32;  nc = NCHK_3; l = 200000; }
        int rel = t - l;
        float ts = 0.f;
        for (int i = lane; i < nc; i += 64) ts += si[(long)m * nc + i];
        ts += __shfl_xor(ts, 1);  ts += __shfl_xor(ts, 2);  ts += __shfl_xor(ts, 4);
        ts += __shfl_xor(ts, 8);  ts += __shfl_xor(ts, 16); ts += __shfl_xor(ts, 32);
        float lse_t = __logf(ts);
        float dt = swz_dot(Hi, m, Wi, rel, K, lane);      // scaled by LOG2E
        nll += lse_t - (dt + bi[rel]) * LN2F;
    }
    if (lane == 0) out[m] = nll;
}

// ---------------- host ----------------
extern "C" void kernel_launch(void* const* d_in, const int* in_sizes, int n_in,
                              void* d_out, int out_size, void* d_ws, size_t ws_size,
                              hipStream_t stream) {
    const float* hidden = (const float*)d_in[0];
    const int*   target = (const int*)d_in[1];
    const float* W0 = (const float*)d_in[2];
    const float* b0 = (const float*)d_in[3];
    const float* p0 = (const float*)d_in[4];
    const float* W1 = (const float*)d_in[5];
    const float* b1 = (const float*)d_in[6];
    const float* p1 = (const float*)d_in[7];
    const float* W2 = (const float*)d_in[8];
    const float* b2 = (const float*)d_in[9];
    const float* p2 = (const float*)d_in[10];
    const float* W3 = (const float*)d_in[11];
    const float* b3 = (const float*)d_in[12];
    const float* p3 = (const float*)d_in[13];
    const float* cw = (const float*)d_in[14];
    const float* cb = (const float*)d_in[15];

    char* ws = (char*)d_ws;
    ushort* hw  = (ushort*)(ws + OFF_HW);
    ushort* ow1 = (ushort*)(ws + OFF_W1);
    ushort* ow2 = (ushort*)(ws + OFF_W2);
    ushort* ow3 = (ushort*)(ws + OFF_W3);
    ushort* hid = (ushort*)(ws + OFF_HID);
    ushort* pT0 = (ushort*)(ws + OFF_PT0);
    ushort* pT1 = (ushort*)(ws + OFF_PT1);
    ushort* pT2 = (ushort*)(ws + OFF_PT2);
    ushort* pT3 = (ushort*)(ws + OFF_PT3);
    ushort* H0  = (ushort*)(ws + OFF_H0);
    ushort* H1  = (ushort*)(ws + OFF_H1);
    ushort* H2  = (ushort*)(ws + OFF_H2);
    ushort* H3  = (ushort*)(ws + OFF_H3);
    float* hbp = (float*)(ws + OFF_HB);
    float* b1p = (float*)(ws + OFF_B1);
    float* b2p = (float*)(ws + OFF_B2);
    float* b3p = (float*)(ws + OFF_B3);
    float* sH  = (float*)(ws + OFF_SH);
    float* s1  = (float*)(ws + OFF_S1);
    float* s2  = (float*)(ws + OFF_S2);
    float* s3  = (float*)(ws + OFF_S3);

    prep_wswz<<<10464, 256, 0, stream>>>(hidden, W0, cw, W1, W2, W3,
                                         p0, p1, p2, p3,
                                         hw, ow1, ow2, ow3, hid, pT0, pT1, pT2, pT3);
    prep_bias<<<1072, 256, 0, stream>>>(b0, b1, b2, b3, cb, hbp, b1p, b2p, b3p);

    gemm_all<<<dim3(NTOK / 64, 44), 256, 0, stream>>>(hid, pT0, pT1, pT2, pT3,
                                                      H0, H1, H2, H3);

    // head: 8 m-blocks x 160 n-blocks
    gemm_lse_k<16><<<1280, 256, 0, stream>>>(H0, hw, hbp, sH, NCHK_H);
    // tail1: K=128
    gemm_lse_k<4><<<1280, 256, 0, stream>>>(H1, ow1, b1p, s1, NCHK_1);
    // tail2: 160 n-groups of 1024 cols
    gemm_lse_n<<<1280, 256, 0, stream>>>(H2, ow2, b2p, s2, NCHK_2, 20, 160);
    // tail3: 67 n-groups (virtual 72)
    gemm_lse_n<<<576, 256, 0, stream>>>(H3, ow3, b3p, s3, NCHK_3, 9, 67);

    finalize_kernel<<<NTOK / 4, 256, 0, stream>>>(target,
        H0, hw, hbp, sH, H1, ow1, b1p, s1, H2, ow2, b2p, s2, H3, ow3, b3p, s3,
        (float*)d_out);
}

// Round 10
// 231.326 us; speedup vs baseline: 2.4263x; 2.1999x over previous
//
#include <hip/hip_runtime.h>

typedef short s16x8 __attribute__((ext_vector_type(8)));
typedef unsigned short u16x8 __attribute__((ext_vector_type(8)));
typedef float f32x4 __attribute__((ext_vector_type(4)));
typedef unsigned short ushort;

// ---------------- problem constants ----------------
#define NTOK 1024
#define DHID 512

#define VH   20003
#define KH   512
#define VH_PAD 20480

#define V1   20000
#define K1   128
#define V1_PAD 20480

#define V2   160000
#define K2   32
#define V2_PAD 163840
#define TPC_2 80       // tiles per chunk (tail2)

#define V3   67735
#define K3   32
#define V3_PAD 68608
#define TPC_3 64       // tiles per chunk (tail3)

// partial-sum chunk counts
#define NCHK_H 320     // 160 n-blocks x 2 col-halves (gemm_lse_k)
#define NCHK_1 320
#define NCHK_2 128     // fused_lse_direct: 1 chunk = 80 tiles
#define NCHK_3 67      // 1 chunk = 64 tiles

#define PAD_BIAS (-1e30f)
#define LOG2E 1.4426950408889634f
#define LN2F  0.6931471805599453f

// Pipeline barrier that is ALSO a compiler fence (r6 inf bug: raw
// __builtin_amdgcn_s_barrier is not an LLVM memory fence; ds_reads were
// hoisted above it and raced other waves' in-flight global_load_lds).
#define PIPE_BARRIER() do {                                   \
        asm volatile("s_barrier" ::: "memory");               \
        __builtin_amdgcn_sched_barrier(0);                    \
    } while (0)

// ---------------- ws layout (bytes) ----------------
#define OFF_HW   0UL
#define OFF_W1   (OFF_HW  + (unsigned long)VH_PAD*KH*2)
#define OFF_W2   (OFF_W1  + (unsigned long)V1_PAD*K1*2)
#define OFF_W3   (OFF_W2  + (unsigned long)V2_PAD*K2*2)
#define OFF_HID  (OFF_W3  + (unsigned long)V3_PAD*K3*2)
#define OFF_PT0  (OFF_HID + (unsigned long)NTOK*DHID*2)
#define OFF_PT1  (OFF_PT0 + (unsigned long)512*DHID*2)
#define OFF_PT2  (OFF_PT1 + (unsigned long)128*DHID*2)
#define OFF_PT3  (OFF_PT2 + (unsigned long)32*DHID*2)
#define OFF_H0   (OFF_PT3 + (unsigned long)32*DHID*2)
#define OFF_H1   (OFF_H0  + (unsigned long)NTOK*512*2)
#define OFF_H2   (OFF_H1  + (unsigned long)NTOK*128*2)
#define OFF_H3   (OFF_H2  + (unsigned long)NTOK*32*2)
#define OFF_HB   (OFF_H3  + (unsigned long)NTOK*32*2)
#define OFF_B1   (OFF_HB  + (unsigned long)VH_PAD*4)
#define OFF_B2   (OFF_B1  + (unsigned long)V1_PAD*4)
#define OFF_B3   (OFF_B2  + (unsigned long)V2_PAD*4)
#define OFF_SH   (OFF_B3  + (unsigned long)V3_PAD*4)
#define OFF_S1   (OFF_SH  + (unsigned long)NTOK*NCHK_H*4)
#define OFF_S2   (OFF_S1  + (unsigned long)NTOK*NCHK_1*4)
#define OFF_S3   (OFF_S2  + (unsigned long)NTOK*NCHK_2*4)

// ---------------- helpers ----------------
__device__ __forceinline__ ushort f2bf(float f) {
    union { float f; unsigned u; } x; x.f = f;
    unsigned r = x.u + 0x7fffu + ((x.u >> 16) & 1u);
    return (ushort)(r >> 16);
}
__device__ __forceinline__ float bf2f(ushort h) {
    union { unsigned u; float f; } x; x.u = ((unsigned)h) << 16;
    return x.f;
}
__device__ __forceinline__ f32x4 mfma_bf16(s16x8 a, s16x8 b, f32x4 c) {
    return __builtin_amdgcn_mfma_f32_16x16x32_bf16(a, b, c, 0, 0, 0);
}
__device__ __forceinline__ void ld8(const float* p, float* v) {
    float4 a = *(const float4*)p, b = *(const float4*)(p + 4);
    v[0]=a.x; v[1]=a.y; v[2]=a.z; v[3]=a.w; v[4]=b.x; v[5]=b.y; v[6]=b.z; v[7]=b.w;
}
__device__ __forceinline__ void gld_lds16(const ushort* g, ushort* l) {
    __builtin_amdgcn_global_load_lds(
        (const __attribute__((address_space(1))) unsigned int*)g,
        (__attribute__((address_space(3))) unsigned int*)l, 16, 0, 0);
}

// ---------------- prep: wave-per-512-element-block swizzle ----------------
// W arrays pre-scaled by LOG2E so fused kernels use exp2; finalize scales by LN2.
#define WB_HW  20480L
#define WB_W1  5120L
#define WB_W2  10240L
#define WB_W3  4288L
#define WB_HID 1024L
#define WB_PT0 512L
#define WB_PT1 128L
#define WB_PT2 32L
#define WB_PT3 32L
#define WB_TOTAL (WB_HW+WB_W1+WB_W2+WB_W3+WB_HID+WB_PT0+WB_PT1+WB_PT2+WB_PT3)

__global__ __launch_bounds__(256) void prep_wswz(
    const float* __restrict__ hidden,
    const float* __restrict__ W0, const float* __restrict__ cw,
    const float* __restrict__ W1, const float* __restrict__ W2, const float* __restrict__ W3,
    const float* __restrict__ p0, const float* __restrict__ p1,
    const float* __restrict__ p2, const float* __restrict__ p3,
    ushort* __restrict__ hw, ushort* __restrict__ ow1,
    ushort* __restrict__ ow2, ushort* __restrict__ ow3,
    ushort* __restrict__ hid,
    ushort* __restrict__ pT0, ushort* __restrict__ pT1,
    ushort* __restrict__ pT2, ushort* __restrict__ pT3)
{
    int lane = threadIdx.x & 63;
    int r = lane & 15, quad = lane >> 4;
    long wb0 = (long)blockIdx.x * 4 + (threadIdx.x >> 6);
    long nw = (long)gridDim.x * 4;
    for (long wb = wb0; wb < WB_TOTAL; wb += nw) {
        long b = wb;
        float vals[8];
        #pragma unroll
        for (int j = 0; j < 8; ++j) vals[j] = 0.f;
        float scale = LOG2E;
        ushort* dst;
        if (b < WB_HW) {
            long tile = b >> 4, ks = b & 15;
            long v = tile * 16 + r, k = ks * 32 + quad * 8;
            if (v < 20000)      ld8(W0 + v * 512 + k, vals);
            else if (v < VH)    ld8(cw + (v - 20000) * 512 + k, vals);
            dst = hw + b * 512 + (long)lane * 8;
        } else if ((b -= WB_HW) < WB_W1) {
            long tile = b >> 2, ks = b & 3;
            long v = tile * 16 + r, k = ks * 32 + quad * 8;
            if (v < V1) ld8(W1 + v * 128 + k, vals);
            dst = ow1 + b * 512 + (long)lane * 8;
        } else if ((b -= WB_W1) < WB_W2) {
            long v = b * 16 + r;
            if (v < V2) ld8(W2 + v * 32 + quad * 8, vals);
            dst = ow2 + b * 512 + (long)lane * 8;
        } else if ((b -= WB_W2) < WB_W3) {
            long v = b * 16 + r;
            if (v < V3 && quad == 0) ld8(W3 + v * 8, vals);
            dst = ow3 + b * 512 + (long)lane * 8;
        } else if ((b -= WB_W3) < WB_HID) {
            scale = 1.f;
            long tile = b >> 4, ks = b & 15;
            long v = tile * 16 + r, k = ks * 32 + quad * 8;
            ld8(hidden + v * 512 + k, vals);
            dst = hid + b * 512 + (long)lane * 8;
        } else if ((b -= WB_HID) < WB_PT0) {
            scale = 1.f;
            long tile = b >> 4, ks = b & 15;
            long c = tile * 16 + r, k = ks * 32 + quad * 8;
            #pragma unroll
            for (int j = 0; j < 8; ++j) vals[j] = p0[(k + j) * 512 + c];
            dst = pT0 + b * 512 + (long)lane * 8;
        } else if ((b -= WB_PT0) < WB_PT1) {
            scale = 1.f;
            long tile = b >> 4, ks = b & 15;
            long c = tile * 16 + r, k = ks * 32 + quad * 8;
            #pragma unroll
            for (int j = 0; j < 8; ++j) vals[j] = p1[(k + j) * 128 + c];
            dst = pT1 + b * 512 + (long)lane * 8;
        } else if ((b -= WB_PT1) < WB_PT2) {
            scale = 1.f;
            long tile = b >> 4, ks = b & 15;
            long c = tile * 16 + r, k = ks * 32 + quad * 8;
            #pragma unroll
            for (int j = 0; j < 8; ++j) vals[j] = p2[(k + j) * 32 + c];
            dst = pT2 + b * 512 + (long)lane * 8;
        } else {
            scale = 1.f;
            b -= WB_PT2;
            long tile = b >> 4, ks = b & 15;
            long c = tile * 16 + r, k = ks * 32 + quad * 8;
            if (c < 8) {
                #pragma unroll
                for (int j = 0; j < 8; ++j) vals[j] = p3[(k + j) * 8 + c];
            }
            dst = pT3 + b * 512 + (long)lane * 8;
        }
        u16x8 o;
        #pragma unroll
        for (int j = 0; j < 8; ++j) o[j] = f2bf(vals[j] * scale);
        *(u16x8*)dst = o;
    }
}

// ---------------- prep: padded biases (pre-scaled by LOG2E) ----------------
#define E_HB  ((long)VH_PAD)
#define E_B1  ((long)V1_PAD)
#define E_B2  ((long)V2_PAD)
#define E_B3  ((long)V3_PAD)
#define E_BIAS (E_HB+E_B1+E_B2+E_B3)

__global__ __launch_bounds__(256) void prep_bias(
    const float* __restrict__ b0, const float* __restrict__ b1,
    const float* __restrict__ b2, const float* __restrict__ b3,
    const float* __restrict__ cb,
    float* __restrict__ hbp, float* __restrict__ ob1,
    float* __restrict__ ob2, float* __restrict__ ob3)
{
    long stride = (long)gridDim.x * blockDim.x;
    for (long i = (long)blockIdx.x * blockDim.x + threadIdx.x; i < E_BIAS; i += stride) {
        long j = i;
        if (j < E_HB) {
            hbp[j] = ((j < 20000) ? b0[j] : (j < VH) ? cb[j - 20000] : PAD_BIAS) * LOG2E;
        } else if ((j -= E_HB) < E_B1) {
            ob1[j] = ((j < V1) ? b1[j] : PAD_BIAS) * LOG2E;
        } else if ((j -= E_B1) < E_B2) {
            ob2[j] = ((j < V2) ? b2[j] : PAD_BIAS) * LOG2E;
        } else { j -= E_B2;
            ob3[j] = ((j < V3) ? b3[j] : PAD_BIAS) * LOG2E;
        }
    }
}

// ---------------- gemm_h body + merged launch ----------------
__device__ __forceinline__ void gemm_body(
    const ushort* __restrict__ A, const ushort* __restrict__ Bt,
    ushort* __restrict__ Hout, int dpad, int c_tile)
{
    int wave = threadIdx.x >> 6, lane = threadIdx.x & 63;
    int quad = lane >> 4, colid = lane & 15;
    int m_tile = blockIdx.x * 4 + wave;
    const ushort* Ab = A + ((long)m_tile * 16) * 512 + lane * 8;
    const ushort* Bb = Bt + ((long)c_tile * 16) * 512 + lane * 8;
    f32x4 acc = {0.f, 0.f, 0.f, 0.f};
    #pragma unroll
    for (int ks = 0; ks < 16; ++ks) {
        s16x8 a = *(const s16x8*)(Ab + ks * 512);
        s16x8 b = *(const s16x8*)(Bb + ks * 512);
        acc = mfma_bf16(a, b, acc);
    }
    int KBo = dpad >> 5;
    int col = c_tile * 16 + colid;
    int ks_o = col >> 5, q_o = (col >> 3) & 3, j_o = col & 7;
    #pragma unroll
    for (int r = 0; r < 4; ++r) {
        int rm = quad * 4 + r;
        Hout[((long)m_tile * KBo + ks_o) * 512 + (q_o * 16 + rm) * 8 + j_o] = f2bf(acc[r]);
    }
}

__global__ __launch_bounds__(256) void gemm_all(
    const ushort* __restrict__ hid,
    const ushort* __restrict__ pT0, const ushort* __restrict__ pT1,
    const ushort* __restrict__ pT2, const ushort* __restrict__ pT3,
    ushort* __restrict__ H0, ushort* __restrict__ H1,
    ushort* __restrict__ H2, ushort* __restrict__ H3)
{
    int y = blockIdx.y;
    if (y < 32)      gemm_body(hid, pT0, H0, 512, y);
    else if (y < 40) gemm_body(hid, pT1, H1, 128, y - 32);
    else if (y < 42) gemm_body(hid, pT2, H2, 32,  y - 40);
    else             gemm_body(hid, pT3, H3, 32,  y - 42);
}

// ============ gemm_lse_k: 128x128 tile, K-pipelined (head KB=16, tail1 KB=4) =========
// (256,2) + fenced barriers — passed r7/r9, out of the top-5; unchanged.
template<int KB>
__global__ __launch_bounds__(256, 2) void gemm_lse_k(
    const ushort* __restrict__ A, const ushort* __restrict__ W,
    const float* __restrict__ biasp, float* __restrict__ part_s,
    int n_chunks)
{
    __shared__ __align__(16) ushort lds[3 * 16 * 512];  // 48 KB: 3 x (A 8KB | B 8KB)
    int bid = blockIdx.x;
    int k = bid & 7, j = bid >> 3;
    int nb = k * 20 + (j >> 3);     // n-block 0..159, XCD-local stripe
    int mb = j & 7;                 // m-block 0..7
    int wave = threadIdx.x >> 6, lane = threadIdx.x & 63;
    int wr = wave >> 1, wc = wave & 1;
    int quad = lane >> 4, colid = lane & 15;

    f32x4 acc[4][4];
    #pragma unroll
    for (int mi = 0; mi < 4; ++mi)
        #pragma unroll
        for (int ni = 0; ni < 4; ++ni) acc[mi][ni] = (f32x4){0.f, 0.f, 0.f, 0.f};

    const long Abase = (long)mb * 8, Wbase = (long)nb * 8;

#define STAGE_K(ks, bf) do {                                                     \
        ushort* d_ = lds + (bf) * (16 * 512);                                    \
        _Pragma("unroll")                                                        \
        for (int i_ = 0; i_ < 2; ++i_) {                                         \
            int t_ = 2 * wave + i_;                                              \
            gld_lds16(A + ((Abase + t_) * KB + (ks)) * 512 + lane * 8,           \
                      d_ + t_ * 512 + lane * 8);                                 \
            gld_lds16(W + ((Wbase + t_) * KB + (ks)) * 512 + lane * 8,           \
                      d_ + (8 + t_) * 512 + lane * 8);                           \
        }                                                                        \
    } while (0)

#define COMP_K(bf) do {                                                          \
        const ushort* b_ = lds + (bf) * (16 * 512);                              \
        s16x8 bfg[4];                                                            \
        _Pragma("unroll")                                                        \
        for (int ni = 0; ni < 4; ++ni)                                           \
            bfg[ni] = *(const s16x8*)(b_ + (8 + wc * 4 + ni) * 512 + lane * 8);  \
        _Pragma("unroll")                                                        \
        for (int mi = 0; mi < 4; ++mi) {                                         \
            s16x8 af = *(const s16x8*)(b_ + (wr * 4 + mi) * 512 + lane * 8);     \
            _Pragma("unroll")                                                    \
            for (int ni = 0; ni < 4; ++ni)                                       \
                acc[mi][ni] = mfma_bf16(af, bfg[ni], acc[mi][ni]);               \
        }                                                                        \
    } while (0)

    STAGE_K(0, 0);
    STAGE_K(1, 1);
    for (int g = 0; g < KB - 1; ++g) {
        asm volatile("s_waitcnt vmcnt(4)" ::: "memory");
        PIPE_BARRIER();
        if (g + 2 < KB) STAGE_K(g + 2, (g + 2) % 3);
        COMP_K(g % 3);
        asm volatile("s_waitcnt lgkmcnt(0)" ::: "memory");
        __builtin_amdgcn_sched_barrier(0);
    }
    asm volatile("s_waitcnt vmcnt(0)" ::: "memory");
    PIPE_BARRIER();
    COMP_K((KB - 1) % 3);
#undef STAGE_K
#undef COMP_K

    // epilogue: bias + exp2 + row-sum over this wave's 64 cols
    float bv[4];
    long c0 = (long)nb * 128 + wc * 64 + colid;
    #pragma unroll
    for (int ni = 0; ni < 4; ++ni) bv[ni] = biasp[c0 + ni * 16];
    int chunk = nb * 2 + wc;
    #pragma unroll
    for (int mi = 0; mi < 4; ++mi) {
        #pragma unroll
        for (int r = 0; r < 4; ++r) {
            float v = 0.f;
            #pragma unroll
            for (int ni = 0; ni < 4; ++ni)
                v += __builtin_amdgcn_exp2f(acc[mi][ni][r] + bv[ni]);
            v += __shfl_xor(v, 1);
            v += __shfl_xor(v, 2);
            v += __shfl_xor(v, 4);
            v += __shfl_xor(v, 8);
            if (colid == 0) {
                int m = mb * 128 + wr * 64 + mi * 16 + quad * 4 + r;
                part_s[(long)m * n_chunks + chunk] = v;
            }
        }
    }
}

// ============ fused_lse_direct: K=32 tails, per-wave direct-load (r0/r3 class) ======
// No LDS, no barriers, no pipeline => no races, live set ~56 regs => no spill.
// KB=1: the A fragment is ONE s16x8 (4 VGPRs). W2 stripe per XCD is L2-resident;
// per-tile stream (1 dwordx4 load + 1 MFMA + 4 exp2 + 4 add) + high occupancy
// hides L2 latency. r7/r8/r9 lesson: the LDS pipeline's register demand cannot
// be bounded at source level; this structure bounds it by construction.
template<int U>
__global__ __launch_bounds__(256) void fused_lse_direct(
    const ushort* __restrict__ A, const ushort* __restrict__ W,
    const float* __restrict__ biasp, float* __restrict__ part_s,
    int tpc, int n_chunks, int cpx)
{
    int bid = blockIdx.x;
    int k = bid & 7, j = bid >> 3;
    int chunk = k * cpx + (j >> 4);   // all 16 m-blocks of a chunk on one XCD
    int mblk = j & 15;
    if (chunk >= n_chunks) return;
    int wave = threadIdx.x >> 6, lane = threadIdx.x & 63;
    int quad = lane >> 4, colid = lane & 15;
    int m_tile = mblk * 4 + wave;     // 0..63
    long t0 = (long)chunk * tpc;

    s16x8 afrag = *(const s16x8*)(A + (long)m_tile * 512 + lane * 8);  // KB=1
    const ushort* Wc = W + t0 * 512;
    const float* bch = biasp + t0 * 16;

    float s_acc[4] = {0.f, 0.f, 0.f, 0.f};
    for (int vt = 0; vt < tpc; vt += U) {
        f32x4 acc[U];
        #pragma unroll
        for (int u = 0; u < U; ++u) {
            float bv = bch[(vt + u) * 16 + colid];
            acc[u] = (f32x4){bv, bv, bv, bv};          // bias folded into init
        }
        #pragma unroll
        for (int u = 0; u < U; ++u) {
            s16x8 b = *(const s16x8*)(Wc + (long)(vt + u) * 512 + lane * 8);
            acc[u] = mfma_bf16(afrag, b, acc[u]);
        }
        #pragma unroll
        for (int u = 0; u < U; ++u)
            #pragma unroll
            for (int r = 0; r < 4; ++r)
                s_acc[r] += __builtin_amdgcn_exp2f(acc[u][r]);
    }
    #pragma unroll
    for (int r = 0; r < 4; ++r) {
        float v = s_acc[r];
        v += __shfl_xor(v, 1);
        v += __shfl_xor(v, 2);
        v += __shfl_xor(v, 4);
        v += __shfl_xor(v, 8);
        if (colid == 0) {
            int m = m_tile * 16 + quad * 4 + r;
            part_s[(long)m * n_chunks + chunk] = v;
        }
    }
}

// ---------------- finalize ----------------
__device__ __forceinline__ float swz_dot(const ushort* __restrict__ H, int m,
                                         const ushort* __restrict__ Wm, long vrow,
                                         int K, int lane)
{
    float d = 0.f;
    if (lane * 8 < K) {
        int ks = lane >> 2, q = lane & 3;
        int KB = K >> 5;
        const ushort* hp = H + ((long)(m >> 4) * KB + ks) * 512 + (q * 16 + (m & 15)) * 8;
        const ushort* wp = Wm + ((vrow >> 4) * KB + ks) * 512 + (q * 16 + (int)(vrow & 15)) * 8;
        #pragma unroll
        for (int j = 0; j < 8; ++j) d += bf2f(hp[j]) * bf2f(wp[j]);
    }
    d += __shfl_xor(d, 1);  d += __shfl_xor(d, 2);  d += __shfl_xor(d, 4);
    d += __shfl_xor(d, 8);  d += __shfl_xor(d, 16); d += __shfl_xor(d, 32);
    return d;
}

__global__ __launch_bounds__(256) void finalize_kernel(
    const int* __restrict__ target,
    const ushort* __restrict__ H0, const ushort* __restrict__ hw,
    const float* __restrict__ hbp, const float* __restrict__ sH,
    const ushort* __restrict__ H1, const ushort* __restrict__ w1,
    const float* __restrict__ b1p, const float* __restrict__ s1,
    const ushort* __restrict__ H2, const ushort* __restrict__ w2,
    const float* __restrict__ b2p, const float* __restrict__ s2,
    const ushort* __restrict__ H3, const ushort* __restrict__ w3,
    const float* __restrict__ b3p, const float* __restrict__ s3,
    float* __restrict__ out)
{
    int wave = threadIdx.x >> 6, lane = threadIdx.x & 63;
    int m = blockIdx.x * 4 + wave;
    int t = target[m];
    int cid = (t >= 20000) + (t >= 40000) + (t >= 200000);

    float s = 0.f;
    for (int i = lane; i < NCHK_H; i += 64) s += sH[(long)m * NCHK_H + i];
    s += __shfl_xor(s, 1);  s += __shfl_xor(s, 2);  s += __shfl_xor(s, 4);
    s += __shfl_xor(s, 8);  s += __shfl_xor(s, 16); s += __shfl_xor(s, 32);
    float lse_h = __logf(s);

    int hc = (cid == 0) ? t : (20003 - cid);
    float d = swz_dot(H0, m, hw, hc, 512, lane);          // scaled by LOG2E
    float nll = lse_h - (d + hbp[hc]) * LN2F;

    if (cid > 0) {
        const ushort *Hi, *Wi; const float *bi, *si; int K, nc, l;
        if (cid == 1)      { Hi = H1; Wi = w1; bi = b1p; si = s1; K = 128; nc = NCHK_1; l = 20000; }
        else if (cid == 2) { Hi = H2; Wi = w2; bi = b2p; si = s2; K = 32;  nc = NCHK_2; l = 40000; }
        else               { Hi = H3; Wi = w3; bi = b3p; si = s3; K = 32;  nc = NCHK_3; l = 200000; }
        int rel = t - l;
        float ts = 0.f;
        for (int i = lane; i < nc; i += 64) ts += si[(long)m * nc + i];
        ts += __shfl_xor(ts, 1);  ts += __shfl_xor(ts, 2);  ts += __shfl_xor(ts, 4);
        ts += __shfl_xor(ts, 8);  ts += __shfl_xor(ts, 16); ts += __shfl_xor(ts, 32);
        float lse_t = __logf(ts);
        float dt = swz_dot(Hi, m, Wi, rel, K, lane);      // scaled by LOG2E
        nll += lse_t - (dt + bi[rel]) * LN2F;
    }
    if (lane == 0) out[m] = nll;
}

// ---------------- host ----------------
extern "C" void kernel_launch(void* const* d_in, const int* in_sizes, int n_in,
                              void* d_out, int out_size, void* d_ws, size_t ws_size,
                              hipStream_t stream) {
    const float* hidden = (const float*)d_in[0];
    const int*   target = (const int*)d_in[1];
    const float* W0 = (const float*)d_in[2];
    const float* b0 = (const float*)d_in[3];
    const float* p0 = (const float*)d_in[4];
    const float* W1 = (const float*)d_in[5];
    const float* b1 = (const float*)d_in[6];
    const float* p1 = (const float*)d_in[7];
    const float* W2 = (const float*)d_in[8];
    const float* b2 = (const float*)d_in[9];
    const float* p2 = (const float*)d_in[10];
    const float* W3 = (const float*)d_in[11];
    const float* b3 = (const float*)d_in[12];
    const float* p3 = (const float*)d_in[13];
    const float* cw = (const float*)d_in[14];
    const float* cb = (const float*)d_in[15];

    char* ws = (char*)d_ws;
    ushort* hw  = (ushort*)(ws + OFF_HW);
    ushort* ow1 = (ushort*)(ws + OFF_W1);
    ushort* ow2 = (ushort*)(ws + OFF_W2);
    ushort* ow3 = (ushort*)(ws + OFF_W3);
    ushort* hid = (ushort*)(ws + OFF_HID);
    ushort* pT0 = (ushort*)(ws + OFF_PT0);
    ushort* pT1 = (ushort*)(ws + OFF_PT1);
    ushort* pT2 = (ushort*)(ws + OFF_PT2);
    ushort* pT3 = (ushort*)(ws + OFF_PT3);
    ushort* H0  = (ushort*)(ws + OFF_H0);
    ushort* H1  = (ushort*)(ws + OFF_H1);
    ushort* H2  = (ushort*)(ws + OFF_H2);
    ushort* H3  = (ushort*)(ws + OFF_H3);
    float* hbp = (float*)(ws + OFF_HB);
    float* b1p = (float*)(ws + OFF_B1);
    float* b2p = (float*)(ws + OFF_B2);
    float* b3p = (float*)(ws + OFF_B3);
    float* sH  = (float*)(ws + OFF_SH);
    float* s1  = (float*)(ws + OFF_S1);
    float* s2  = (float*)(ws + OFF_S2);
    float* s3  = (float*)(ws + OFF_S3);

    prep_wswz<<<10464, 256, 0, stream>>>(hidden, W0, cw, W1, W2, W3,
                                         p0, p1, p2, p3,
                                         hw, ow1, ow2, ow3, hid, pT0, pT1, pT2, pT3);
    prep_bias<<<1072, 256, 0, stream>>>(b0, b1, b2, b3, cb, hbp, b1p, b2p, b3p);

    gemm_all<<<dim3(NTOK / 64, 44), 256, 0, stream>>>(hid, pT0, pT1, pT2, pT3,
                                                      H0, H1, H2, H3);

    // head: 8 m-blocks x 160 n-blocks
    gemm_lse_k<16><<<1280, 256, 0, stream>>>(H0, hw, hbp, sH, NCHK_H);
    // tail1: K=128
    gemm_lse_k<4><<<1280, 256, 0, stream>>>(H1, ow1, b1p, s1, NCHK_1);
    // tail2: 128 chunks x 16 m-blocks, 16 chunks/XCD
    fused_lse_direct<8><<<2048, 256, 0, stream>>>(H2, ow2, b2p, s2, TPC_2, NCHK_2, 16);
    // tail3: 67 chunks (virtual 72), 9 chunks/XCD
    fused_lse_direct<8><<<1152, 256, 0, stream>>>(H3, ow3, b3p, s3, TPC_3, NCHK_3, 9);

    finalize_kernel<<<NTOK / 4, 256, 0, stream>>>(target,
        H0, hw, hbp, sH, H1, ow1, b1p, s1, H2, ow2, b2p, s2, H3, ow3, b3p, s3,
        (float*)d_out);
}